// Round 15
// baseline (192.271 us; speedup 1.0000x reference)
//
#include <hip/hip_runtime.h>
#include <math.h>

// ws footprint: 50,331,648 bytes (decay table lives in the free region).
#define B_  2
#define T_  2048
#define C_  1024
#define NH_ 16
#define HD_ 64
#define N3_ 3072

typedef float f32x4 __attribute__((ext_vector_type(4)));
typedef short bf16x8 __attribute__((ext_vector_type(8)));
typedef unsigned short u16;
typedef float f32x4_base __attribute__((ext_vector_type(4)));
typedef f32x4_base __attribute__((aligned(4))) f32x4u;   // 4B-aligned vector load

// Q prescale: 1/sqrt(64) * log2(e), so softmax uses exp2 directly.
#define QSCALE 0.18033688011112042f

#if __has_builtin(__builtin_amdgcn_exp2f)
#define EXP2(x) __builtin_amdgcn_exp2f(x)
#else
#define EXP2(x) exp2f(x)
#endif

__device__ __forceinline__ u16 f2bf(float x) {
  unsigned int u = __builtin_bit_cast(unsigned int, x);
  u += 0x7FFFu + ((u >> 16) & 1u);
  return (u16)(u >> 16);
}

__device__ __forceinline__ unsigned int cvt_pk_bf16(float lo, float hi) {
  unsigned int r;
  asm("v_cvt_pk_bf16_f32 %0, %1, %2" : "=v"(r) : "v"(lo), "v"(hi));
  return r;
}

#define GLD16(g, l) __builtin_amdgcn_global_load_lds( \
    (__attribute__((address_space(1))) void*)(g), \
    (__attribute__((address_space(3))) void*)(l), 16, 0, 0)

// ---------------- fused prep: x->bf16, Wa^T, Wp^T, decay table ----------------
__global__ __launch_bounds__(256) void prep_kernel(
    const float* __restrict__ x, u16* __restrict__ xb,
    const float* __restrict__ Wa, u16* __restrict__ WaT,
    const float* __restrict__ Wp, u16* __restrict__ WpT,
    float* __restrict__ decR)
{
  __shared__ float tile[32][33];
  const int bid = blockIdx.x;
  const int tid = threadIdx.x;
  if (bid < 4096) {
    int i = (bid * 256 + tid) * 4;
    float4 v = *(const float4*)(x + i);
    ushort4 o;
    o.x = f2bf(v.x); o.y = f2bf(v.y); o.z = f2bf(v.z); o.w = f2bf(v.w);
    *(ushort4*)(xb + i) = o;
  } else if (bid < 8192) {
    const float* in; u16* out; int Cc, c0, r0;
    if (bid < 7168) {
      int t = bid - 4096;
      in = Wa; out = WaT; Cc = N3_;
      c0 = (t % 96) * 32; r0 = (t / 96) * 32;
    } else {
      int t = bid - 7168;
      in = Wp; out = WpT; Cc = C_;
      c0 = (t % 32) * 32; r0 = (t / 32) * 32;
    }
    int tx = tid & 31, ty = tid >> 5;
#pragma unroll
    for (int rr = ty; rr < 32; rr += 8)
      tile[rr][tx] = in[(size_t)(r0 + rr) * Cc + c0 + tx];
    __syncthreads();
#pragma unroll
    for (int rr = ty; rr < 32; rr += 8)
      out[(size_t)(c0 + rr) * 1024 + r0 + tx] = f2bf(tile[tx][rr]);
  } else {
    int j = (bid - 8192) * 256 + tid;
    if (j < 4352) {
      int d = 2047 - j;
      float v = 1.0f;
      if (d >= 15) v = 1.0f - powf((float)(d - 15) * (1.0f / 2032.0f), 0.36787944117144233f);
      decR[j] = v;
    }
  }
}

// ---------------- gemm0: 256x256 tile, BK=64, 8 waves, 8-phase (R14) ---------
__global__ void __launch_bounds__(512, 1) gemm256_kernel(
    const u16* __restrict__ A, const u16* __restrict__ Bt,
    u16* __restrict__ Cq, u16* __restrict__ Vt,
    int M, int N, int K)
{
  extern __shared__ char lds[];   // A: buf*32768 + half*16384; B: 65536 + same
  const int tid = threadIdx.x;
  const int lane = tid & 63;
  const int wave = tid >> 6;
  const int wm = wave >> 2;        // 0..1 (M half)
  const int wn = wave & 3;         // 0..3 (N quarter)
  const int quad = lane >> 4;
  const int l15 = lane & 15;
  const int nxb = N >> 8;
  const int orig = blockIdx.x;
  const int cpx = (int)gridDim.x >> 3;
  const int wg = (orig & 7) * cpx + (orig >> 3);
  const int m0 = (wg / nxb) << 8;
  const int n0 = (wg % nxb) << 8;

  f32x4 acc[8][4] = {};

  const int abase = wm * 16384;                    // + buf*32768
  const int bbase = 65536 + (wn >> 1) * 16384;     // + buf*32768
  const int brow0 = (wn & 1) * 64;

#define HSTAGE(arr, rowbase, tile, ldsoff)                                       \
  {                                                                              \
    _Pragma("unroll")                                                            \
    for (int p = 0; p < 2; ++p) {                                                \
      int chunk = p * 8192 + tid * 16;                                           \
      int row = chunk >> 7;                                                      \
      int colb = (chunk & 127) ^ ((row & 7) << 4);                               \
      GLD16((const char*)((arr) + (size_t)((rowbase) + row) * K + (size_t)(tile) * 64) + colb, \
            lds + (ldsoff) + chunk);                                             \
    }                                                                            \
  }

#define PHASE(mg, buf, BLOAD, WAIT, STAGE_STMT)                                  \
  {                                                                              \
    if (WAIT) asm volatile("s_waitcnt vmcnt(4)" ::: "memory");                   \
    __builtin_amdgcn_s_barrier();                                                \
    __builtin_amdgcn_sched_barrier(0);                                           \
    STAGE_STMT;                                                                  \
    if (BLOAD) {                                                                 \
      _Pragma("unroll")                                                          \
      for (int n = 0; n < 4; ++n) {                                              \
        int rl = brow0 + n * 16 + l15;                                           \
        int msk = (rl & 7) << 4;                                                 \
        bfr[n][0] = *(const bf16x8*)(lds + bbase + (buf) * 32768 + rl * 128 +    \
                                     ((quad * 16) ^ msk));                       \
        bfr[n][1] = *(const bf16x8*)(lds + bbase + (buf) * 32768 + rl * 128 +    \
                                     ((64 + quad * 16) ^ msk));                  \
      }                                                                          \
    }                                                                            \
    bf16x8 af[2][2];                                                             \
    _Pragma("unroll")                                                            \
    for (int mm = 0; mm < 2; ++mm) {                                             \
      int rl = (mg) * 32 + mm * 16 + l15;                                        \
      int msk = (rl & 7) << 4;                                                   \
      af[mm][0] = *(const bf16x8*)(lds + abase + (buf) * 32768 + rl * 128 +      \
                                   ((quad * 16) ^ msk));                         \
      af[mm][1] = *(const bf16x8*)(lds + abase + (buf) * 32768 + rl * 128 +      \
                                   ((64 + quad * 16) ^ msk));                    \
    }                                                                            \
    __builtin_amdgcn_s_setprio(1);                                               \
    _Pragma("unroll")                                                            \
    for (int mm = 0; mm < 2; ++mm)                                               \
      _Pragma("unroll")                                                          \
      for (int n = 0; n < 4; ++n) {                                              \
        acc[(mg) * 2 + mm][n] = __builtin_amdgcn_mfma_f32_16x16x32_bf16(         \
            af[mm][0], bfr[n][0], acc[(mg) * 2 + mm][n], 0, 0, 0);               \
        acc[(mg) * 2 + mm][n] = __builtin_amdgcn_mfma_f32_16x16x32_bf16(         \
            af[mm][1], bfr[n][1], acc[(mg) * 2 + mm][n], 0, 0, 0);               \
      }                                                                          \
    __builtin_amdgcn_s_setprio(0);                                               \
  }

  bf16x8 bfr[4][2];

  // prologue: B(0)+A(0) -> buf0, B(1) -> buf1-B
  HSTAGE(Bt, n0 + 0,   0, 65536 + 0);
  HSTAGE(Bt, n0 + 128, 0, 65536 + 16384);
  HSTAGE(A,  m0 + 0,   0, 0);
  HSTAGE(A,  m0 + 128, 0, 16384);
  HSTAGE(Bt, n0 + 0,   1, 65536 + 32768);
  HSTAGE(Bt, n0 + 128, 1, 65536 + 32768 + 16384);

  const int nt = K >> 6;        // 16 tiles
  const int tm = nt - 1;        // clamp mask (nt is a power of 2)
  for (int j = 0; j < nt / 2; ++j) {
    const int t1 = 2 * j + 1, t2 = (2 * j + 2) & tm, t3 = (2 * j + 3) & tm;
    // phases 1-4: compute tile 2j (buf0)
    PHASE(0, 0, true,  true,  HSTAGE(A, m0 + 0,   t1, 32768));
    PHASE(1, 0, false, false, HSTAGE(A, m0 + 128, t1, 32768 + 16384));
    PHASE(2, 0, false, false, HSTAGE(Bt, n0 + 0,   t2, 65536));
    PHASE(3, 0, false, false, HSTAGE(Bt, n0 + 128, t2, 65536 + 16384));
    // phases 5-8: compute tile 2j+1 (buf1)
    PHASE(0, 1, true,  true,  HSTAGE(A, m0 + 0,   t2, 0));
    PHASE(1, 1, false, false, HSTAGE(A, m0 + 128, t2, 16384));
    PHASE(2, 1, false, false, HSTAGE(Bt, n0 + 0,   t3, 65536 + 32768));
    PHASE(3, 1, false, false, HSTAGE(Bt, n0 + 128, t3, 65536 + 32768 + 16384));
  }
#undef PHASE
#undef HSTAGE

  // epilogue: scatter Q (prescaled), K into qkb; V transposed into VT
#pragma unroll
  for (int m = 0; m < 8; ++m) {
    int grow0 = m0 + wm * 128 + m * 16 + quad * 4;
#pragma unroll
    for (int n = 0; n < 4; ++n) {
      int gcol = n0 + wn * 64 + n * 16 + l15;
      f32x4 v = acc[m][n];
      int bb = grow0 >> 11, tt0 = grow0 & 2047;
      int which = gcol >> 10, rem = gcol & 1023;
      int hh = rem >> 6, dd = rem & 63;
      if (which < 2) {
#pragma unroll
        for (int r = 0; r < 4; ++r) {
          float ov = (which == 0) ? v[r] * QSCALE : v[r];
          Cq[((size_t)(which * 32 + bb * 16 + hh) * 2048 + tt0 + r) * 64 + dd] = f2bf(ov);
        }
      } else {
        ushort4 o;
        o.x = f2bf(v[0]); o.y = f2bf(v[1]); o.z = f2bf(v[2]); o.w = f2bf(v[3]);
        *(ushort4*)(Vt + ((size_t)(bb * 16 + hh) * 64 + dd) * 2048 + tt0) = o;
      }
    }
  }
}

// ---------------- gemm1: 128x128, counted vmcnt, fp32 out --------------------
__global__ __launch_bounds__(256, 3) void gemm128_kernel(
    const u16* __restrict__ A, const u16* __restrict__ Bt,
    float* __restrict__ Cf, int M, int N, int K)
{
  __shared__ char lds[49152];
  const int lane = threadIdx.x & 63;
  const int wave = threadIdx.x >> 6;
  const int nxb = N >> 7;
  const int orig = blockIdx.x;
  const int cpx = (int)gridDim.x >> 3;
  const int wg = (orig & 7) * cpx + (orig >> 3);
  const int m0 = (wg / nxb) << 7;
  const int n0 = (wg % nxb) << 7;
  const int wm = wave >> 1, wn = wave & 1;

  f32x4 acc[4][4] = {};

#define GSTAGE(buf, k0)                                                          \
  {                                                                              \
    _Pragma("unroll")                                                            \
    for (int c = 0; c < 2; ++c) {                                                \
      int chunk = wave * 2048 + c * 1024;                                        \
      int row = (chunk >> 6) + (lane >> 2);                                      \
      int wb = ((lane & 3) << 4) ^ ((row & 3) << 4);                             \
      GLD16((const char*)(A  + (size_t)(m0 + row) * K + (k0)) + wb,              \
            lds + (buf) * 16384 + chunk);                                        \
      GLD16((const char*)(Bt + (size_t)(n0 + row) * K + (k0)) + wb,              \
            lds + (buf) * 16384 + 8192 + chunk);                                 \
    }                                                                            \
  }

  const int nk = K >> 5;
  GSTAGE(0, 0);
  GSTAGE(1, 32);
  __syncthreads();

  for (int i = 0; i < nk; ++i) {
    if (i + 1 < nk) asm volatile("s_waitcnt vmcnt(4)" ::: "memory");
    else            asm volatile("s_waitcnt vmcnt(0)" ::: "memory");
    __builtin_amdgcn_s_barrier();
    __builtin_amdgcn_sched_barrier(0);
    if (i + 2 < nk) GSTAGE((i + 2) % 3, (i + 2) * 32);

    const char* base = lds + (i % 3) * 16384;
    bf16x8 af[4], bfr[4];
#pragma unroll
    for (int m = 0; m < 4; ++m) {
      int row = wm * 64 + m * 16 + (lane & 15);
      int wb = ((lane >> 4) << 4) ^ ((row & 3) << 4);
      af[m] = *(const bf16x8*)(base + row * 64 + wb);
    }
#pragma unroll
    for (int n = 0; n < 4; ++n) {
      int row = wn * 64 + n * 16 + (lane & 15);
      int wb = ((lane >> 4) << 4) ^ ((row & 3) << 4);
      bfr[n] = *(const bf16x8*)(base + 8192 + row * 64 + wb);
    }
    __builtin_amdgcn_s_setprio(1);
#pragma unroll
    for (int m = 0; m < 4; ++m)
#pragma unroll
      for (int n = 0; n < 4; ++n)
        acc[m][n] = __builtin_amdgcn_mfma_f32_16x16x32_bf16(af[m], bfr[n], acc[m][n], 0, 0, 0);
    __builtin_amdgcn_s_setprio(0);
  }

#pragma unroll
  for (int m = 0; m < 4; ++m) {
    int grow0 = m0 + wm * 64 + m * 16 + ((lane >> 4) << 2);
#pragma unroll
    for (int n = 0; n < 4; ++n) {
      int gcol = n0 + wn * 64 + n * 16 + (lane & 15);
      f32x4 v = acc[m][n];
#pragma unroll
      for (int r = 0; r < 4; ++r)
        Cf[(size_t)(grow0 + r) * N + gcol] = v[r];
    }
  }
#undef GSTAGE
}

// ---------------- fused flash attention, NO K/V staging (L2-direct) ----------
// K/V per XCD = 2MB, L2-resident (4MB). Fragments read straight from global:
// no klds/vlds, no global_load_lds, no vmcnt asm, and -- since plds rows are
// wave-private -- NO BARRIERS in the loop. 4 waves/block read identical 16KB
// per iter near-lockstep -> L1 serves re-reads. LDS pipe only carries P.
// grid 1024, one 64-row q-tile per block, heavy-first dispatch (R9 mapping),
// 4 blocks/CU (launch_bounds(256,4), LDS 9.7KB).
__global__ __launch_bounds__(256, 4) void attn_kernel(
    const u16* __restrict__ qkb, const u16* __restrict__ vtg,
    const float* __restrict__ decR, u16* __restrict__ yb)
{
  __shared__ u16 plds[64 * 76];    // P [q][key], stride 76, wave-private rows

  const int lane = threadIdx.x & 63;
  const int wave = threadIdx.x >> 6;
  const int quad = lane >> 4;
  const int l15 = lane & 15;
  const int orig = blockIdx.x;
  const int x = orig & 31;
  const int bh = ((x & 7) << 2) + (x >> 3);    // 4 heads per XCD
  const int g = orig >> 5;
  const int j3 = g >> 3;                       // dispatch class, 0 first
  const int g0 = g & 7;
  const int qt = (3 - j3) * 8 + ((j3 & 1) ? (7 - g0) : g0);   // heavy first
  const int b = bh >> 4, h = bh & 15;

  const u16* Q   = qkb + (size_t)bh * T_ * HD_;
  const u16* Kg  = qkb + (size_t)(32 + bh) * T_ * HD_;
  const u16* VTg = vtg + (size_t)bh * HD_ * T_;

  const int wrow = qt * 64 + wave * 16;
  const int q = wrow + l15;            // this lane's S^T column (global q)
  const float* dp = decR + (2047 - q + quad * 4);

  bf16x8 qa[2];
  { const u16* qp = Q + (size_t)q * HD_ + quad * 8;
    qa[0] = *(const bf16x8*)qp; qa[1] = *(const bf16x8*)(qp + 32); }

  f32x4 acc[4] = {};
  float lsum = 0.0f;

  for (int kt = 0; kt <= qt; ++kt) {
    // K fragments direct from global (L1/L2-hot): same bytes as the staged path
    const u16* Kt = Kg + (size_t)(kt * 64) * HD_;
    bf16x8 kf[4][2];
#pragma unroll
    for (int f = 0; f < 4; ++f) {
      const u16* kp = Kt + (size_t)(f * 16 + l15) * HD_ + quad * 8;
      kf[f][0] = *(const bf16x8*)(kp);
      kf[f][1] = *(const bf16x8*)(kp + 32);
    }

    // decay factors: one dwordx4 per f-block (L1-hot table)
    f32x4 dc[4];
    const float* dk = dp + kt * 64;
#pragma unroll
    for (int f = 0; f < 4; ++f) dc[f] = *(const f32x4u*)(dk + f * 16);

    // S^T = K Q^T (log2 domain): col=q=l15, row=key=f*16+quad*4+r
    f32x4 s[4];
    __builtin_amdgcn_s_setprio(1);
#pragma unroll
    for (int f = 0; f < 4; ++f) {
      f32x4 t = {};
      t = __builtin_amdgcn_mfma_f32_16x16x32_bf16(kf[f][0], qa[0], t, 0, 0, 0);
      t = __builtin_amdgcn_mfma_f32_16x16x32_bf16(kf[f][1], qa[1], t, 0, 0, 0);
      s[f] = t;
    }
    __builtin_amdgcn_s_setprio(0);

    if (kt == qt) {   // diagonal: mask key > q
#pragma unroll
      for (int f = 0; f < 4; ++f) {
        int key0 = kt * 64 + f * 16 + quad * 4;
#pragma unroll
        for (int r = 0; r < 4; ++r)
          if (key0 + r > q) s[f][r] = -1e30f;
      }
    }

    // softmax: denom = sum exp2(s); numerator = exp2(s)*decay -> packed bf16
#pragma unroll
    for (int f = 0; f < 4; ++f) {
      f32x4 p;
#pragma unroll
      for (int r = 0; r < 4; ++r) p[r] = EXP2(s[f][r]);
      lsum += (p[0] + p[1]) + (p[2] + p[3]);
      unsigned int w0 = cvt_pk_bf16(p[0] * dc[f][0], p[1] * dc[f][1]);
      unsigned int w1 = cvt_pk_bf16(p[2] * dc[f][2], p[3] * dc[f][3]);
      uint2 wv; wv.x = w0; wv.y = w1;
      *(uint2*)(plds + (size_t)(wave * 16 + l15) * 76 + f * 16 + quad * 4) = wv;
    }

    // V^T fragments direct from global (shared data, L1 catches re-reads)
    bf16x8 vf[4][2];
#pragma unroll
    for (int n = 0; n < 4; ++n) {
      const u16* vp = VTg + (size_t)(n * 16 + l15) * T_ + kt * 64 + quad * 8;
#pragma unroll
      for (int ks = 0; ks < 2; ++ks)
        vf[n][ks] = *(const bf16x8*)(vp + ks * 32);
    }

    // y += P @ V (plds rows wave-private: in-wave lgkm ordering suffices)
    bf16x8 pa0 = *(const bf16x8*)(plds + (size_t)(wave * 16 + l15) * 76 + quad * 8);
    bf16x8 pa1 = *(const bf16x8*)(plds + (size_t)(wave * 16 + l15) * 76 + 32 + quad * 8);
    __builtin_amdgcn_s_setprio(1);
#pragma unroll
    for (int n = 0; n < 4; ++n) {
      acc[n] = __builtin_amdgcn_mfma_f32_16x16x32_bf16(pa0, vf[n][0], acc[n], 0, 0, 0);
      acc[n] = __builtin_amdgcn_mfma_f32_16x16x32_bf16(pa1, vf[n][1], acc[n], 0, 0, 0);
    }
    __builtin_amdgcn_s_setprio(0);
  }

  // finalize: denom for q=l15 -> reduce across quads, broadcast to q=quad*4+r
  lsum += __shfl_xor(lsum, 16); lsum += __shfl_xor(lsum, 32);
  float rb[4];
#pragma unroll
  for (int r = 0; r < 4; ++r)
    rb[r] = 1.0f / __shfl(lsum, quad * 4 + r, 16);
#pragma unroll
  for (int n = 0; n < 4; ++n) {
    int d = h * 64 + n * 16 + l15;
#pragma unroll
    for (int r = 0; r < 4; ++r) {
      int t = wrow + quad * 4 + r;
      yb[((size_t)b * T_ + t) * 1024 + d] = f2bf(acc[n][r] * rb[r]);
    }
  }
}

// ---------------- launch ----------------
extern "C" void kernel_launch(void* const* d_in, const int* in_sizes, int n_in,
                              void* d_out, int out_size, void* d_ws, size_t ws_size,
                              hipStream_t stream) {
  const float* x  = (const float*)d_in[0];
  const float* Wa = (const float*)d_in[1];
  const float* Wp = (const float*)d_in[2];
  float* out = (float*)d_out;
  char* ws = (char*)d_ws;

  // workspace layout (bytes), total 50,331,648
  u16*   xb    = (u16*)(ws + 0);           //  8,388,608  x bf16; reused as yb
  u16*   WaT   = (u16*)(ws + 8388608);     //  6,291,456  W_attn^T bf16
  u16*   WpT   = (u16*)(ws + 14680064);    //  2,097,152  W_proj^T bf16
  u16*   qkb   = (u16*)(ws + 16777216);    // 16,777,216  Q,K bf16 [2][32][2048][64]
  float* decR  = (float*)(ws + 33554432);  //     17,408  reversed padded decay (4352)
  u16*   VT    = (u16*)(ws + 41943040);    //  8,388,608  V^T bf16 [32][64][2048]
  u16*   yb    = xb;

  // unconditional (deterministic, idempotent; not a stream op)
  hipFuncSetAttribute((const void*)gemm256_kernel,
                      hipFuncAttributeMaxDynamicSharedMemorySize, 131072);

  prep_kernel<<<8209, 256, 0, stream>>>(x, xb, Wa, WaT, Wp, WpT, decR);
  gemm256_kernel<<<192, 512, 131072, stream>>>(xb, WaT, qkb, VT, B_ * T_, N3_, C_);
  attn_kernel<<<1024, 256, 0, stream>>>(qkb, VT, decR, yb);
  gemm128_kernel<<<256, 256, 0, stream>>>(yb, WpT, out, B_ * T_, 1024, 1024);
}